// Round 9
// baseline (1781.800 us; speedup 1.0000x reference)
//
#include <hip/hip_runtime.h>
#include <stdint.h>

// LSTM_Trend: B=256, T=512, F=64, H=512, P=24.
// Persistent kernel: 256 WGs x 256 threads (1/CU) = 16 batch-groups (16 rows)
// x 16 hidden-groups (32 h-units = 128 gate cols). Weights register-resident
// as MFMA B-fragments (2 subtiles x 18 K-iters); one A-frag feeds 2 MFMAs.
// Round-9 structure (2 barriers/step, no Gls, no dedicated pollers):
//   S1 -> MFMA -> in-register quad transpose (shfl_xor 1,2) -> activations in
//   the acc-holding lanes -> h published as 2-byte sc0sc1 stores -> vmcnt(0)
//   -> S3 -> flag store (remapped slot) -> per-thread poll of its OWN flag
//   quad (one dwordx4) -> per-thread h data loads -> LDS stage -> loop.
// Exchange is r6's proven protocol: plain sc0sc1 (L1/L2-bypass, L3-coherent)
// stores/loads, zero cache-maintenance ops, no atomics (r8: RMW serialization
// made atomics slower). Flag freshness: producer drains h (vmcnt0+S3) before
// flag store; consumer issues data loads only after observing flag >= t+1.

namespace {
constexpr int T_STEPS = 512;
constexpr int FEA  = 64;
constexpr int HID  = 512;
constexpr int KTOT = HID + FEA;   // 576
constexpr int KPAD = KTOT + 8;    // 584 bf16 = 1168 B rows (16B skew)
constexpr int NKI  = KTOT / 32;   // 18 K-iterations
constexpr int RPG  = 16;          // batch rows per group
constexpr size_t HBUF_HALF = 256ull * 512;          // uint16 elems per buffer
constexpr size_t BAR_OFF   = 2 * HBUF_HALF * 2;     // byte offset of flags

typedef __bf16   bf16x8 __attribute__((ext_vector_type(8)));
typedef uint16_t u16x8  __attribute__((ext_vector_type(8)));
typedef float    f32x4  __attribute__((ext_vector_type(4)));
typedef uint32_t u32x4  __attribute__((ext_vector_type(4)));

union V8 { u16x8 u; bf16x8 b; u32x4 q; };

__device__ __forceinline__ float bf2f(uint16_t u) {
  union { uint32_t i; float f; } v; v.i = (uint32_t)u << 16; return v.f;
}
__device__ __forceinline__ uint16_t f2bf(float f) {
  union { float f; uint32_t i; } v; v.f = f;
  uint32_t x = v.i;
  return (uint16_t)((x + 0x7FFFu + ((x >> 16) & 1u)) >> 16);  // RNE
}
__device__ __forceinline__ float sigmoid_f(float x) {
  return 1.0f / (1.0f + __expf(-x));
}
__device__ __forceinline__ float tanh_f(float x) {
  float e = __expf(-2.0f * fabsf(x));
  float t = (1.0f - e) / (1.0f + e);
  return copysignf(t, x);
}
__device__ __forceinline__ bf16x8 load8(const void* base, size_t elem_off,
                                        bool fp32m) {
  V8 r;
  if (fp32m) {
    const float* p = (const float*)base + elem_off;
#pragma unroll
    for (int i = 0; i < 8; ++i) r.u[i] = f2bf(p[i]);
  } else {
    r.q = *(const u32x4*)((const uint16_t*)base + elem_off);
  }
  return r.b;
}
__device__ __forceinline__ float loadf(const void* base, int idx, bool fp32m) {
  return fp32m ? ((const float*)base)[idx] : bf2f(((const uint16_t*)base)[idx]);
}

// ---- explicit L3-coherent (L1/L2-bypass) memory ops -----------------------
__device__ __forceinline__ u32x4 ld128_sc01(const uint32_t* p) {
  u32x4 v;
  asm volatile("global_load_dwordx4 %0, %1, off sc0 sc1"
               : "=v"(v) : "v"(p) : "memory");
  return v;
}
__device__ __forceinline__ void st32_sc01(uint32_t* p, uint32_t v) {
  asm volatile("global_store_dword %0, %1, off sc0 sc1"
               :: "v"(p), "v"(v) : "memory");
}
__device__ __forceinline__ void st16_sc01(uint16_t* p, uint32_t v) {
  asm volatile("global_store_short %0, %1, off sc0 sc1"
               :: "v"(p), "v"(v) : "memory");
}
__device__ __forceinline__ void waitcnt_vm0() {
  asm volatile("s_waitcnt vmcnt(0)" ::: "memory");
}

// 4x4 transpose across a lane-quad: in: lane j holds a_e = M[j][e];
// out: lane j holds a_e = M[e][j].  (2 rounds of shfl_xor -> DPP/swizzle)
__device__ __forceinline__ void tp4(float& a0, float& a1, float& a2, float& a3,
                                    int j) {
  float t0 = __shfl_xor((j & 1) ? a0 : a1, 1, 64);
  float t1 = __shfl_xor((j & 1) ? a2 : a3, 1, 64);
  if (j & 1) { a0 = t0; a2 = t1; } else { a1 = t0; a3 = t1; }
  float t2 = __shfl_xor((j & 2) ? a0 : a2, 2, 64);
  float t3 = __shfl_xor((j & 2) ? a1 : a3, 2, 64);
  if (j & 2) { a0 = t2; a1 = t3; } else { a2 = t2; a3 = t3; }
}
} // namespace

__global__ __launch_bounds__(256, 1) void lstm_persistent(
    const void* __restrict__ x,      // [256][512][64]
    const void* __restrict__ W_ih,   // [2048][64]
    const void* __restrict__ W_hh,   // [2048][512]
    const void* __restrict__ b_ih,   // [2048]
    const void* __restrict__ b_hh,   // [2048]
    const void* __restrict__ W_fc,   // [1536][512]
    const void* __restrict__ b_fc,   // [1536]
    void* __restrict__ out,          // [256][1536]
    uint16_t* __restrict__ hbuf,     // [2][256][512] bf16 (workspace)
    uint32_t* __restrict__ bar)      // 16 groups x 16 flag dwords (64B/line)
{
  __shared__ uint16_t Als[RPG * KPAD];   // A tile: [h_{t-1} | x_t], 16 rows
  __shared__ int      sflag;

  const int tid = threadIdx.x;
  const int wv  = tid >> 6;              // wave 0..3
  const int ln  = tid & 63;
  const int nl  = ln & 15;               // MFMA m/n lane index
  const int kq  = ln >> 4;               // MFMA k-quad
  const int q   = nl >> 2;               // quad index within 16-lane group
  const int jg  = nl & 3;                // gate index of this lane's col
  const int bg  = blockIdx.x & 15;       // batch group
  const int wgi = blockIdx.x >> 4;       // hidden group 0..15
  const int r0  = bg * RPG;              // first batch row of this group

  // ---- dtype sniff (block-uniform): fp32 read as bf16 -> huge exponents
  if (tid == 0) sflag = 0;
  __syncthreads();
  {
    float a = fabsf(bf2f(((const uint16_t*)b_ih)[tid]));
    if (a > 1.0f) atomicOr(&sflag, 1);
  }
  __syncthreads();
  const bool fp32m = (sflag != 0);

  // wave owns cols [wv*32, wv*32+32) as two 16-col subtiles sharing one A-frag
  // col = 4*unit + gate (i,f,g,o of one h-unit in 4 adjacent lanes)
  bf16x8 breg[2][NKI];
  float  bias[2];
#pragma unroll
  for (int s = 0; s < 2; ++s) {
    int col  = wv * 32 + s * 16 + nl;
    int gate = col & 3;
    int unit = col >> 2;
    int gcol = gate * HID + wgi * 32 + unit;
#pragma unroll
    for (int kk = 0; kk < NKI; ++kk) {
      int k0 = kk * 32 + kq * 8;
      if (k0 < HID)
        breg[s][kk] = load8(W_hh, (size_t)gcol * HID + k0, fp32m);
      else
        breg[s][kk] = load8(W_ih, (size_t)gcol * FEA + (k0 - HID), fp32m);
    }
    bias[s] = loadf(b_ih, gcol, fp32m) + loadf(b_hh, gcol, fp32m);
  }

  // post-transpose ownership: this lane = batch row (kq*4+jg), units u0,u1
  const int row = kq * 4 + jg;
  const int u0  = wv * 8 + q;            // subtile-0 unit (0..31 local)
  const int u1  = u0 + 4;                // subtile-1 unit
  float c0 = 0.0f, c1 = 0.0f;

  const int srow = tid >> 4;             // staging row
  const int l16  = tid & 15;
  uint16_t* Ar = &Als[srow * KPAD];

  uint32_t* fl = bar + bg * 16;          // this group's 64B flag line
  const int fidx = (wgi & 3) * 4 + (wgi >> 2);   // producer's remapped slot
  const uint32_t* fq = fl + (l16 >> 2) * 4;      // consumer's flag quad

  const size_t xrow = (size_t)(r0 + srow) * (T_STEPS * FEA) + l16 * 4;

  // ---- prologue: h_0 = 0 in LDS, stage x_0 ----
  {
    u32x4 z = {0, 0, 0, 0};
#pragma unroll
    for (int i = 0; i < 4; ++i) *(u32x4*)&Ar[(l16 + 16 * i) * 8] = z;
    uint2 w;
    if (fp32m) {
      const float4 xv = *(const float4*)((const float*)x + xrow);
      w.x = (uint32_t)f2bf(xv.x) | ((uint32_t)f2bf(xv.y) << 16);
      w.y = (uint32_t)f2bf(xv.z) | ((uint32_t)f2bf(xv.w) << 16);
    } else {
      w = *(const uint2*)((const uint16_t*)x + xrow);
    }
    *(uint2*)&Ar[HID + l16 * 4] = w;
  }

  for (int t = 0; t < T_STEPS; ++t) {
    const bool havex = (t + 1 < T_STEPS);
    // x(t+1) global prefetch into regs (latency hidden under MFMA)
    uint2 xw;
    if (havex) {
      size_t off = xrow + (size_t)(t + 1) * FEA;
      if (fp32m) {
        const float4 xv = *(const float4*)((const float*)x + off);
        xw.x = (uint32_t)f2bf(xv.x) | ((uint32_t)f2bf(xv.y) << 16);
        xw.y = (uint32_t)f2bf(xv.z) | ((uint32_t)f2bf(xv.w) << 16);
      } else {
        xw = *(const uint2*)((const uint16_t*)x + off);
      }
    }

    __syncthreads();                     // S1: A tile staged

    // ---- gates = A @ W^T + bias: 18 K-steps, 1 A-frag -> 2 MFMAs ----
    f32x4 acc0, acc1;
    acc0[0] = bias[0]; acc0[1] = bias[0]; acc0[2] = bias[0]; acc0[3] = bias[0];
    acc1[0] = bias[1]; acc1[1] = bias[1]; acc1[2] = bias[1]; acc1[3] = bias[1];
#pragma unroll
    for (int kk = 0; kk < NKI; ++kk) {
      bf16x8 a = *(const bf16x8*)&Als[nl * KPAD + kk * 32 + kq * 8];
      acc0 = __builtin_amdgcn_mfma_f32_16x16x32_bf16(a, breg[0][kk], acc0, 0, 0, 0);
      acc1 = __builtin_amdgcn_mfma_f32_16x16x32_bf16(a, breg[1][kk], acc1, 0, 0, 0);
    }

    // ---- in-register quad transpose -> this lane holds (i,f,g,o) ----
    float g00 = acc0[0], g01 = acc0[1], g02 = acc0[2], g03 = acc0[3];
    float g10 = acc1[0], g11 = acc1[1], g12 = acc1[2], g13 = acc1[3];
    tp4(g00, g01, g02, g03, jg);         // gates of (row, unit u0)
    tp4(g10, g11, g12, g13, jg);         // gates of (row, unit u1)

    // ---- activations, cell update, 2-byte h publish (sc0sc1 -> L3) ----
    {
      c0 = sigmoid_f(g01) * c0 + sigmoid_f(g00) * tanh_f(g02);
      float h0 = sigmoid_f(g03) * tanh_f(c0);
      c1 = sigmoid_f(g11) * c1 + sigmoid_f(g10) * tanh_f(g12);
      float h1 = sigmoid_f(g13) * tanh_f(c1);
      uint16_t* hw = hbuf + (size_t)((t + 1) & 1) * HBUF_HALF
                     + (size_t)(r0 + row) * 512 + wgi * 32;
      st16_sc01(hw + u0, (uint32_t)f2bf(h0));
      st16_sc01(hw + u1, (uint32_t)f2bf(h1));
    }
    waitcnt_vm0();                       // this wave's h at L3
    __syncthreads();                     // S3: whole WG's h drained

    if (tid == 0) st32_sc01(fl + fidx, (uint32_t)(t + 1));
    if (havex) *(uint2*)&Ar[HID + l16 * 4] = xw;   // x(t+1) into LDS

    // ---- fused per-thread poll (own flag quad) + own h data loads ----
    {
      const uint32_t target = (uint32_t)(t + 1);
      for (;;) {
        u32x4 f = ld128_sc01(fq);
        waitcnt_vm0();
        if (f[0] >= target && f[1] >= target && f[2] >= target &&
            f[3] >= target) break;
        __builtin_amdgcn_s_sleep(1);
      }
      if (havex) {
        const uint32_t* src =
            (const uint32_t*)(hbuf + (size_t)((t + 1) & 1) * HBUF_HALF)
            + (size_t)(r0 + srow) * 256;
        u32x4 v0 = ld128_sc01(src + (l16 + 0)  * 4);
        u32x4 v1 = ld128_sc01(src + (l16 + 16) * 4);
        u32x4 v2 = ld128_sc01(src + (l16 + 32) * 4);
        u32x4 v3 = ld128_sc01(src + (l16 + 48) * 4);
        waitcnt_vm0();
        *(u32x4*)&Ar[(l16 + 0)  * 8] = v0;
        *(u32x4*)&Ar[(l16 + 16) * 8] = v1;
        *(u32x4*)&Ar[(l16 + 32) * 8] = v2;
        *(u32x4*)&Ar[(l16 + 48) * 8] = v3;
      }
    }
  }

  // ---- FC head: out = h_T @ W_fc^T + b_fc  (h_T is in buffer 0) ----
  const uint32_t* hn = (const uint32_t*)hbuf;
  int gwave = wgi * 4 + wv;              // 0..63 within the batch group
  for (int tile = gwave; tile < 96; tile += 64) {
    int n = tile * 16 + nl;              // out column
    float bs = loadf(b_fc, n, fp32m);
    f32x4 acc; acc[0] = bs; acc[1] = bs; acc[2] = bs; acc[3] = bs;
#pragma unroll
    for (int kk = 0; kk < 16; ++kk) {
      int k0 = kk * 32 + kq * 8;
      V8 av;
      av.q = ld128_sc01(hn + (size_t)(r0 + nl) * 256 + (k0 >> 1));
      bf16x8 b = load8(W_fc, (size_t)n * HID + k0, fp32m);
      waitcnt_vm0();
      acc = __builtin_amdgcn_mfma_f32_16x16x32_bf16(av.b, b, acc, 0, 0, 0);
    }
#pragma unroll
    for (int r = 0; r < 4; ++r) {
      int orow = r0 + kq * 4 + r;
      if (fp32m) ((float*)out)[(size_t)orow * 1536 + n] = acc[r];
      else       ((uint16_t*)out)[(size_t)orow * 1536 + n] = f2bf(acc[r]);
    }
  }
}

extern "C" void kernel_launch(void* const* d_in, const int* in_sizes, int n_in,
                              void* d_out, int out_size, void* d_ws, size_t ws_size,
                              hipStream_t stream) {
  const void* x    = d_in[0];
  const void* W_ih = d_in[1];
  const void* W_hh = d_in[2];
  const void* b_ih = d_in[3];
  const void* b_hh = d_in[4];
  const void* W_fc = d_in[5];
  const void* b_fc = d_in[6];
  uint16_t* hbuf = (uint16_t*)d_ws;
  uint32_t* bar  = (uint32_t*)((char*)d_ws + BAR_OFF);

  // flags must start at 0 (ws is poisoned 0xAA; 0xAAAAAAAA >= target would
  // pass polls early with garbage h)
  hipMemsetAsync((void*)bar, 0, 16 * 16 * sizeof(uint32_t), stream);

  lstm_persistent<<<dim3(256), dim3(256), 0, stream>>>(
      x, W_ih, W_hh, b_ih, b_hh, W_fc, b_fc, d_out, hbuf, bar);
}

// Round 10
// 1651.436 us; speedup vs baseline: 1.0789x; 1.0789x over previous
//
#include <hip/hip_runtime.h>
#include <stdint.h>

// LSTM_Trend: B=256, T=512, F=64, H=512, P=24.
// Persistent kernel: 256 WGs x 256 threads (1/CU) = 16 batch-groups (16 rows)
// x 16 hidden-groups (32 h-units = 128 gate cols). Weights register-resident
// as MFMA B-fragments (2 subtiles x 18 K-iters); one A-frag feeds 2 MFMAs.
// Round-10 = round-9 structure with COALESCED h publish restored:
//   S1 -> MFMA -> in-register quad transpose (shfl_xor 1,2) -> activations ->
//   h (2x bf16) into 1KB LDS tile -> S2b -> one packed dword per thread,
//   64B-coalesced global_store_dword sc0 sc1 -> vmcnt(0) -> S3 -> flag store
//   (remapped slot) -> per-thread poll of its OWN flag quad (one dwordx4) ->
//   per-thread h loads -> LDS stage -> loop.   3 barriers/step.
// r9 lesson: scattered 2B sc0sc1 stores caused 3.9x write amplification
// (WRITE_SIZE 137->530MB) -- write-through-no-allocate pays per-burst.
// Exchange protocol unchanged from r6 (plain sc0sc1, L1/L2-bypass, zero
// cache-maintenance, no atomics; r8 showed far atomics serialize at RMW).

namespace {
constexpr int T_STEPS = 512;
constexpr int FEA  = 64;
constexpr int HID  = 512;
constexpr int KTOT = HID + FEA;   // 576
constexpr int KPAD = KTOT + 8;    // 584 bf16 = 1168 B rows (16B skew)
constexpr int NKI  = KTOT / 32;   // 18 K-iterations
constexpr int RPG  = 16;          // batch rows per group
constexpr size_t HBUF_HALF = 256ull * 512;          // uint16 elems per buffer
constexpr size_t BAR_OFF   = 2 * HBUF_HALF * 2;     // byte offset of flags

typedef __bf16   bf16x8 __attribute__((ext_vector_type(8)));
typedef uint16_t u16x8  __attribute__((ext_vector_type(8)));
typedef float    f32x4  __attribute__((ext_vector_type(4)));
typedef uint32_t u32x4  __attribute__((ext_vector_type(4)));

union V8 { u16x8 u; bf16x8 b; u32x4 q; };

__device__ __forceinline__ float bf2f(uint16_t u) {
  union { uint32_t i; float f; } v; v.i = (uint32_t)u << 16; return v.f;
}
__device__ __forceinline__ uint16_t f2bf(float f) {
  union { float f; uint32_t i; } v; v.f = f;
  uint32_t x = v.i;
  return (uint16_t)((x + 0x7FFFu + ((x >> 16) & 1u)) >> 16);  // RNE
}
__device__ __forceinline__ float sigmoid_f(float x) {
  return 1.0f / (1.0f + __expf(-x));
}
__device__ __forceinline__ float tanh_f(float x) {
  float e = __expf(-2.0f * fabsf(x));
  float t = (1.0f - e) / (1.0f + e);
  return copysignf(t, x);
}
__device__ __forceinline__ bf16x8 load8(const void* base, size_t elem_off,
                                        bool fp32m) {
  V8 r;
  if (fp32m) {
    const float* p = (const float*)base + elem_off;
#pragma unroll
    for (int i = 0; i < 8; ++i) r.u[i] = f2bf(p[i]);
  } else {
    r.q = *(const u32x4*)((const uint16_t*)base + elem_off);
  }
  return r.b;
}
__device__ __forceinline__ float loadf(const void* base, int idx, bool fp32m) {
  return fp32m ? ((const float*)base)[idx] : bf2f(((const uint16_t*)base)[idx]);
}

// ---- explicit L3-coherent (L1/L2-bypass) memory ops -----------------------
__device__ __forceinline__ u32x4 ld128_sc01(const uint32_t* p) {
  u32x4 v;
  asm volatile("global_load_dwordx4 %0, %1, off sc0 sc1"
               : "=v"(v) : "v"(p) : "memory");
  return v;
}
__device__ __forceinline__ void st32_sc01(uint32_t* p, uint32_t v) {
  asm volatile("global_store_dword %0, %1, off sc0 sc1"
               :: "v"(p), "v"(v) : "memory");
}
__device__ __forceinline__ void waitcnt_vm0() {
  asm volatile("s_waitcnt vmcnt(0)" ::: "memory");
}

// 4x4 transpose across a lane-quad: in: lane j holds a_e = M[j][e];
// out: lane j holds a_e = M[e][j].  (2 rounds of shfl_xor -> DPP/swizzle)
__device__ __forceinline__ void tp4(float& a0, float& a1, float& a2, float& a3,
                                    int j) {
  float t0 = __shfl_xor((j & 1) ? a0 : a1, 1, 64);
  float t1 = __shfl_xor((j & 1) ? a2 : a3, 1, 64);
  if (j & 1) { a0 = t0; a2 = t1; } else { a1 = t0; a3 = t1; }
  float t2 = __shfl_xor((j & 2) ? a0 : a2, 2, 64);
  float t3 = __shfl_xor((j & 2) ? a1 : a3, 2, 64);
  if (j & 2) { a0 = t2; a1 = t3; } else { a2 = t2; a3 = t3; }
}
} // namespace

__global__ __launch_bounds__(256, 1) void lstm_persistent(
    const void* __restrict__ x,      // [256][512][64]
    const void* __restrict__ W_ih,   // [2048][64]
    const void* __restrict__ W_hh,   // [2048][512]
    const void* __restrict__ b_ih,   // [2048]
    const void* __restrict__ b_hh,   // [2048]
    const void* __restrict__ W_fc,   // [1536][512]
    const void* __restrict__ b_fc,   // [1536]
    void* __restrict__ out,          // [256][1536]
    uint16_t* __restrict__ hbuf,     // [2][256][512] bf16 (workspace)
    uint32_t* __restrict__ bar)      // 16 groups x 16 flag dwords (64B/line)
{
  __shared__ uint16_t Als[RPG * KPAD];   // A tile: [h_{t-1} | x_t], 16 rows
  __shared__ uint16_t Hls[RPG * 32];     // 1KB: this WG's h slice, row-major
  __shared__ int      sflag;

  const int tid = threadIdx.x;
  const int wv  = tid >> 6;              // wave 0..3
  const int ln  = tid & 63;
  const int nl  = ln & 15;               // MFMA m/n lane index
  const int kq  = ln >> 4;               // MFMA k-quad
  const int q   = nl >> 2;               // quad index within 16-lane group
  const int jg  = nl & 3;                // gate index of this lane's col
  const int bg  = blockIdx.x & 15;       // batch group
  const int wgi = blockIdx.x >> 4;       // hidden group 0..15
  const int r0  = bg * RPG;              // first batch row of this group

  // ---- dtype sniff (block-uniform): fp32 read as bf16 -> huge exponents
  if (tid == 0) sflag = 0;
  __syncthreads();
  {
    float a = fabsf(bf2f(((const uint16_t*)b_ih)[tid]));
    if (a > 1.0f) atomicOr(&sflag, 1);
  }
  __syncthreads();
  const bool fp32m = (sflag != 0);

  // wave owns cols [wv*32, wv*32+32) as two 16-col subtiles sharing one A-frag
  // col = 4*unit + gate (i,f,g,o of one h-unit in 4 adjacent lanes)
  bf16x8 breg[2][NKI];
  float  bias[2];
#pragma unroll
  for (int s = 0; s < 2; ++s) {
    int col  = wv * 32 + s * 16 + nl;
    int gate = col & 3;
    int unit = col >> 2;
    int gcol = gate * HID + wgi * 32 + unit;
#pragma unroll
    for (int kk = 0; kk < NKI; ++kk) {
      int k0 = kk * 32 + kq * 8;
      if (k0 < HID)
        breg[s][kk] = load8(W_hh, (size_t)gcol * HID + k0, fp32m);
      else
        breg[s][kk] = load8(W_ih, (size_t)gcol * FEA + (k0 - HID), fp32m);
    }
    bias[s] = loadf(b_ih, gcol, fp32m) + loadf(b_hh, gcol, fp32m);
  }

  // post-transpose ownership: this lane = batch row (kq*4+jg), units u0,u1
  const int row = kq * 4 + jg;
  const int u0  = wv * 8 + q;            // subtile-0 unit (0..31 local)
  const int u1  = u0 + 4;                // subtile-1 unit
  float c0 = 0.0f, c1 = 0.0f;

  const int srow = tid >> 4;             // staging / copy-out row
  const int l16  = tid & 15;
  uint16_t* Ar = &Als[srow * KPAD];

  uint32_t* fl = bar + bg * 16;          // this group's 64B flag line
  const int fidx = (wgi & 3) * 4 + (wgi >> 2);   // producer's remapped slot
  const uint32_t* fq = fl + (l16 >> 2) * 4;      // consumer's flag quad

  const size_t xrow = (size_t)(r0 + srow) * (T_STEPS * FEA) + l16 * 4;

  // ---- prologue: h_0 = 0 in LDS, stage x_0 ----
  {
    u32x4 z = {0, 0, 0, 0};
#pragma unroll
    for (int i = 0; i < 4; ++i) *(u32x4*)&Ar[(l16 + 16 * i) * 8] = z;
    uint2 w;
    if (fp32m) {
      const float4 xv = *(const float4*)((const float*)x + xrow);
      w.x = (uint32_t)f2bf(xv.x) | ((uint32_t)f2bf(xv.y) << 16);
      w.y = (uint32_t)f2bf(xv.z) | ((uint32_t)f2bf(xv.w) << 16);
    } else {
      w = *(const uint2*)((const uint16_t*)x + xrow);
    }
    *(uint2*)&Ar[HID + l16 * 4] = w;
  }

  for (int t = 0; t < T_STEPS; ++t) {
    const bool havex = (t + 1 < T_STEPS);
    // x(t+1) global prefetch into regs (latency hidden under MFMA)
    uint2 xw;
    if (havex) {
      size_t off = xrow + (size_t)(t + 1) * FEA;
      if (fp32m) {
        const float4 xv = *(const float4*)((const float*)x + off);
        xw.x = (uint32_t)f2bf(xv.x) | ((uint32_t)f2bf(xv.y) << 16);
        xw.y = (uint32_t)f2bf(xv.z) | ((uint32_t)f2bf(xv.w) << 16);
      } else {
        xw = *(const uint2*)((const uint16_t*)x + off);
      }
    }

    __syncthreads();                     // S1: A tile staged

    // ---- gates = A @ W^T + bias: 18 K-steps, 1 A-frag -> 2 MFMAs ----
    f32x4 acc0, acc1;
    acc0[0] = bias[0]; acc0[1] = bias[0]; acc0[2] = bias[0]; acc0[3] = bias[0];
    acc1[0] = bias[1]; acc1[1] = bias[1]; acc1[2] = bias[1]; acc1[3] = bias[1];
#pragma unroll
    for (int kk = 0; kk < NKI; ++kk) {
      bf16x8 a = *(const bf16x8*)&Als[nl * KPAD + kk * 32 + kq * 8];
      acc0 = __builtin_amdgcn_mfma_f32_16x16x32_bf16(a, breg[0][kk], acc0, 0, 0, 0);
      acc1 = __builtin_amdgcn_mfma_f32_16x16x32_bf16(a, breg[1][kk], acc1, 0, 0, 0);
    }

    // ---- in-register quad transpose -> this lane holds (i,f,g,o) ----
    float g00 = acc0[0], g01 = acc0[1], g02 = acc0[2], g03 = acc0[3];
    float g10 = acc1[0], g11 = acc1[1], g12 = acc1[2], g13 = acc1[3];
    tp4(g00, g01, g02, g03, jg);         // gates of (row, unit u0)
    tp4(g10, g11, g12, g13, jg);         // gates of (row, unit u1)

    // ---- activations, cell update, h -> 1KB LDS tile ----
    {
      c0 = sigmoid_f(g01) * c0 + sigmoid_f(g00) * tanh_f(g02);
      float h0 = sigmoid_f(g03) * tanh_f(c0);
      c1 = sigmoid_f(g11) * c1 + sigmoid_f(g10) * tanh_f(g12);
      float h1 = sigmoid_f(g13) * tanh_f(c1);
      Hls[row * 32 + u0] = f2bf(h0);
      Hls[row * 32 + u1] = f2bf(h1);
    }
    __syncthreads();                     // S2b: h tile complete in LDS

    // ---- coalesced publish: one packed dword per thread (64B lines) ----
    {
      uint32_t v = *(const uint32_t*)&Hls[srow * 32 + l16 * 2];
      uint32_t* hw = (uint32_t*)(hbuf + (size_t)((t + 1) & 1) * HBUF_HALF)
                     + (size_t)(r0 + srow) * 256 + wgi * 16 + l16;
      st32_sc01(hw, v);
    }
    waitcnt_vm0();                       // this wave's h publish drained
    __syncthreads();                     // S3: whole WG's h drained

    if (tid == 0) st32_sc01(fl + fidx, (uint32_t)(t + 1));
    if (havex) *(uint2*)&Ar[HID + l16 * 4] = xw;   // x(t+1) into LDS

    // ---- fused per-thread poll (own flag quad) + own h data loads ----
    {
      const uint32_t target = (uint32_t)(t + 1);
      for (;;) {
        u32x4 f = ld128_sc01(fq);
        waitcnt_vm0();
        if (f[0] >= target && f[1] >= target && f[2] >= target &&
            f[3] >= target) break;
        __builtin_amdgcn_s_sleep(1);
      }
      if (havex) {
        const uint32_t* src =
            (const uint32_t*)(hbuf + (size_t)((t + 1) & 1) * HBUF_HALF)
            + (size_t)(r0 + srow) * 256;
        u32x4 v0 = ld128_sc01(src + (l16 + 0)  * 4);
        u32x4 v1 = ld128_sc01(src + (l16 + 16) * 4);
        u32x4 v2 = ld128_sc01(src + (l16 + 32) * 4);
        u32x4 v3 = ld128_sc01(src + (l16 + 48) * 4);
        waitcnt_vm0();
        *(u32x4*)&Ar[(l16 + 0)  * 8] = v0;
        *(u32x4*)&Ar[(l16 + 16) * 8] = v1;
        *(u32x4*)&Ar[(l16 + 32) * 8] = v2;
        *(u32x4*)&Ar[(l16 + 48) * 8] = v3;
      }
    }
  }

  // ---- FC head: out = h_T @ W_fc^T + b_fc  (h_T is in buffer 0) ----
  const uint32_t* hn = (const uint32_t*)hbuf;
  int gwave = wgi * 4 + wv;              // 0..63 within the batch group
  for (int tile = gwave; tile < 96; tile += 64) {
    int n = tile * 16 + nl;              // out column
    float bs = loadf(b_fc, n, fp32m);
    f32x4 acc; acc[0] = bs; acc[1] = bs; acc[2] = bs; acc[3] = bs;
#pragma unroll
    for (int kk = 0; kk < 16; ++kk) {
      int k0 = kk * 32 + kq * 8;
      V8 av;
      av.q = ld128_sc01(hn + (size_t)(r0 + nl) * 256 + (k0 >> 1));
      bf16x8 b = load8(W_fc, (size_t)n * HID + k0, fp32m);
      waitcnt_vm0();
      acc = __builtin_amdgcn_mfma_f32_16x16x32_bf16(av.b, b, acc, 0, 0, 0);
    }
#pragma unroll
    for (int r = 0; r < 4; ++r) {
      int orow = r0 + kq * 4 + r;
      if (fp32m) ((float*)out)[(size_t)orow * 1536 + n] = acc[r];
      else       ((uint16_t*)out)[(size_t)orow * 1536 + n] = f2bf(acc[r]);
    }
  }
}

extern "C" void kernel_launch(void* const* d_in, const int* in_sizes, int n_in,
                              void* d_out, int out_size, void* d_ws, size_t ws_size,
                              hipStream_t stream) {
  const void* x    = d_in[0];
  const void* W_ih = d_in[1];
  const void* W_hh = d_in[2];
  const void* b_ih = d_in[3];
  const void* b_hh = d_in[4];
  const void* W_fc = d_in[5];
  const void* b_fc = d_in[6];
  uint16_t* hbuf = (uint16_t*)d_ws;
  uint32_t* bar  = (uint32_t*)((char*)d_ws + BAR_OFF);

  // flags must start at 0 (ws is poisoned 0xAA; 0xAAAAAAAA >= target would
  // pass polls early with garbage h)
  hipMemsetAsync((void*)bar, 0, 16 * 16 * sizeof(uint32_t), stream);

  lstm_persistent<<<dim3(256), dim3(256), 0, stream>>>(
      x, W_ih, W_hh, b_ih, b_hh, W_fc, b_fc, d_out, hbuf, bar);
}